// Round 3
// baseline (480.259 us; speedup 1.0000x reference)
//
#include <hip/hip_runtime.h>
#include <hip/hip_bf16.h>
#include <cstdint>

typedef __attribute__((ext_vector_type(8))) short short8;
typedef __attribute__((ext_vector_type(4))) short short4_;
typedef __attribute__((ext_vector_type(4))) float float4_;

#define MFMA16(a,b,c) __builtin_amdgcn_mfma_f32_16x16x32_bf16(a,b,c,0,0,0)

__device__ __forceinline__ float bf2f(const __hip_bfloat16 h) { return __bfloat162float(h); }
__device__ __forceinline__ short f2bs(float f) {
    __hip_bfloat16 h = __float2bfloat16(f);
    return *reinterpret_cast<short*>(&h);
}
__device__ __forceinline__ float s2f(short s) {
    return __bfloat162float(*reinterpret_cast<__hip_bfloat16*>(&s));
}

static const int EMB = 256;
static const int SEQ = 4096;   // 64*64 spatial
static const int TOK = 16384;  // BS * SEQ

// ---------------------------------------------------------------- repack ----
// fp32 weights -> bf16, transposed to [n][k]. Fold 1/8 attn scale into wqT.
__global__ __launch_bounds__(256) void repack_kernel(
    const float* wq, const float* wk, const float* wv,
    const float* wo, const float* w1, const float* w2,
    short* wqT, short* wkT, short* wvT, short* woT, short* w1T, short* w2T)
{
    int idx = blockIdx.x * 256 + threadIdx.x;
    if (idx < 3 * 4096) {
        int m = idx / 4096, r = idx % 4096;
        int n = r / 64, k = r % 64;
        const float* src = (m == 0) ? wq : (m == 1) ? wk : wv;
        short* dst = (m == 0) ? wqT : (m == 1) ? wkT : wvT;
        float v = src[k * 64 + n];
        if (m == 0) v *= 0.125f;
        dst[n * 64 + k] = f2bs(v);
    } else {
        int idx2 = idx - 3 * 4096;
        if (idx2 < 3 * 65536) {
            int m = idx2 / 65536, r = idx2 % 65536;
            int n = r / 256, k = r % 256;
            const float* src = (m == 0) ? wo : (m == 1) ? w1 : w2;
            short* dst = (m == 0) ? woT : (m == 1) ? w1T : w2T;
            dst[n * 256 + k] = f2bs(src[k * 256 + n]);
        }
    }
}

// ------------------------------------------------------------------- ln1 ----
// x fp32 [b][c][sp] -> xn bf16 [t][c] (normalized) and xt bf16 [t][c].
__global__ __launch_bounds__(64) void ln1_kernel(
    const float* x, const float* g, const float* bta,
    short* xn, short* xt)
{
    int t = blockIdx.x * 64 + threadIdx.x;
    int b = t >> 12, sp = t & 4095;
    const float* xb = x + (size_t)b * EMB * SEQ + sp;
    float sum = 0.f, ss = 0.f;
#pragma unroll 8
    for (int c = 0; c < 256; c++) {
        float v = xb[(size_t)c * SEQ];
        sum += v; ss += v * v;
    }
    float mu = sum * (1.f / 256.f);
    float var = ss * (1.f / 256.f) - mu * mu;
    float rs = rsqrtf(var + 1e-5f);
    short* xnr = xn + (size_t)t * 256;
    short* xtr = xt + (size_t)t * 256;
#pragma unroll 8
    for (int c = 0; c < 256; c++) {
        float v = xb[(size_t)c * SEQ];
        xtr[c] = f2bs(v);
        xnr[c] = f2bs((v - mu) * rs * g[c] + bta[c]);
    }
}

// ------------------------------------------------------------------- qkv ----
// q,k stored [bh][s][d]; v stored transposed [bh][d][s] for flash B-frags.
__global__ __launch_bounds__(256) void qkv_kernel(
    const short* xn, const short* wqT, const short* wkT, const short* wvT,
    const float* bq, const float* bk, const float* bv,
    short* qo, short* ko, short* vto)
{
    int tid = threadIdx.x;
    int w = tid >> 6, lane = tid & 63, quad = lane >> 4, l15 = lane & 15;
    int m0 = blockIdx.x * 64 + w * 16;
    int row = m0 + l15;
    int bb = row >> 12;
    int s0 = (m0 & 4095) + quad * 4;

    for (int h = 0; h < 4; h++) {
        short8 a0 = *(const short8*)(xn + (size_t)row * 256 + h * 64 + quad * 8);
        short8 a1 = *(const short8*)(xn + (size_t)row * 256 + h * 64 + 32 + quad * 8);
        size_t headbase = (size_t)(bb * 4 + h) * SEQ;
#pragma unroll
        for (int p = 0; p < 3; p++) {
            const short* WT = (p == 0) ? wqT : (p == 1) ? wkT : wvT;
            const float* bias = (p == 0) ? bq : (p == 1) ? bk : bv;
            float bscale = (p == 0) ? 0.125f : 1.f;
#pragma unroll
            for (int nb = 0; nb < 4; nb++) {
                int col = nb * 16 + l15;
                short8 b0 = *(const short8*)(WT + col * 64 + quad * 8);
                short8 b1 = *(const short8*)(WT + col * 64 + 32 + quad * 8);
                float bvv = bias[col] * bscale;
                float4_ acc = {bvv, bvv, bvv, bvv};
                acc = MFMA16(a0, b0, acc);
                acc = MFMA16(a1, b1, acc);
                if (p < 2) {
                    short* dst = (p == 0) ? qo : ko;
#pragma unroll
                    for (int r = 0; r < 4; r++)
                        dst[(headbase + s0 + r) * 64 + col] = f2bs(acc[r]);
                } else {
                    short4_ pk;
#pragma unroll
                    for (int r = 0; r < 4; r++) pk[r] = f2bs(acc[r]);
                    *(short4_*)(vto + ((size_t)(bb * 4 + h) * 64 + col) * SEQ + s0) = pk;
                }
            }
        }
    }
}

// ----------------------------------------------------------------- flash ----
// Per (q-tile 64, bh): loop 64 K-tiles; online softmax; P via LDS layout swap.
// LDS pitch 72 bf16 = 144 B: 16B-aligned, bank step 36 == 4 mod 32 -> 2-way (free).
__global__ __launch_bounds__(256) void flash_kernel(
    const short* q, const short* k, const short* vt, short* o)
{
    __shared__ short K_lds[64 * 72];
    __shared__ short V_lds[64 * 72];
    __shared__ short P_lds[64 * 72];

    int tid = threadIdx.x;
    int w = tid >> 6, lane = tid & 63, quad = lane >> 4, l15 = lane & 15;
    int qt = blockIdx.x, bh = blockIdx.y;

    const short* qb = q + (size_t)bh * SEQ * 64;
    const short* kb = k + (size_t)bh * SEQ * 64;
    const short* vb = vt + (size_t)bh * 64 * SEQ;

    int qrow = qt * 64 + w * 16 + l15;
    short8 qf0 = *(const short8*)(qb + (size_t)qrow * 64 + quad * 8);
    short8 qf1 = *(const short8*)(qb + (size_t)qrow * 64 + 32 + quad * 8);

    float4_ oacc[4];
#pragma unroll
    for (int nb = 0; nb < 4; nb++) oacc[nb] = {0.f, 0.f, 0.f, 0.f};
    float mi[4], li[4];
#pragma unroll
    for (int r = 0; r < 4; r++) { mi[r] = -1e30f; li[r] = 0.f; }

    int srow = tid >> 2;          // 0..63
    int sc0 = (tid & 3) * 8;      // 0,8,16,24 (+32 second pass)
    int pbase = w * 16 * 72;

    for (int kt = 0; kt < 64; kt++) {
        __syncthreads();
#pragma unroll
        for (int i = 0; i < 2; i++) {
            *(short8*)&K_lds[srow * 72 + sc0 + i * 32] =
                *(const short8*)(kb + (size_t)(kt * 64 + srow) * 64 + sc0 + i * 32);
            *(short8*)&V_lds[srow * 72 + sc0 + i * 32] =
                *(const short8*)(vb + (size_t)srow * SEQ + kt * 64 + sc0 + i * 32);
        }
        __syncthreads();

        // S = Q K^T  (scale prefolded into wq)
        float4_ s[4];
#pragma unroll
        for (int nb = 0; nb < 4; nb++) {
            float4_ a = {0.f, 0.f, 0.f, 0.f};
            short8 b0 = *(const short8*)&K_lds[(nb * 16 + l15) * 72 + quad * 8];
            short8 b1 = *(const short8*)&K_lds[(nb * 16 + l15) * 72 + 32 + quad * 8];
            a = MFMA16(qf0, b0, a);
            a = MFMA16(qf1, b1, a);
            s[nb] = a;
        }

        // online softmax update
        float mnew[4], alpha[4];
#pragma unroll
        for (int r = 0; r < 4; r++) {
            float t = fmaxf(fmaxf(s[0][r], s[1][r]), fmaxf(s[2][r], s[3][r]));
            t = fmaxf(t, __shfl_xor(t, 1));
            t = fmaxf(t, __shfl_xor(t, 2));
            t = fmaxf(t, __shfl_xor(t, 4));
            t = fmaxf(t, __shfl_xor(t, 8));
            mnew[r] = fmaxf(mi[r], t);
            alpha[r] = __expf(mi[r] - mnew[r]);
            mi[r] = mnew[r];
        }
#pragma unroll
        for (int nb = 0; nb < 4; nb++)
#pragma unroll
            for (int r = 0; r < 4; r++)
                s[nb][r] = __expf(s[nb][r] - mnew[r]);
#pragma unroll
        for (int r = 0; r < 4; r++) {
            float rs = s[0][r] + s[1][r] + s[2][r] + s[3][r];
            rs += __shfl_xor(rs, 1);
            rs += __shfl_xor(rs, 2);
            rs += __shfl_xor(rs, 4);
            rs += __shfl_xor(rs, 8);
            li[r] = li[r] * alpha[r] + rs;
#pragma unroll
            for (int nb = 0; nb < 4; nb++) oacc[nb][r] *= alpha[r];
        }

        // P: C-layout -> LDS -> A-layout (per-wave private 16-row region)
#pragma unroll
        for (int nb = 0; nb < 4; nb++)
#pragma unroll
            for (int r = 0; r < 4; r++)
                P_lds[pbase + (quad * 4 + r) * 72 + nb * 16 + l15] = f2bs(s[nb][r]);

#pragma unroll
        for (int c = 0; c < 2; c++) {
            short8 pa = *(const short8*)&P_lds[pbase + l15 * 72 + c * 32 + quad * 8];
#pragma unroll
            for (int nb = 0; nb < 4; nb++) {
                short8 vbf = *(const short8*)&V_lds[(nb * 16 + l15) * 72 + c * 32 + quad * 8];
                oacc[nb] = MFMA16(pa, vbf, oacc[nb]);
            }
        }
    }

    // epilogue: normalize and store merged-head o [t][c]
    int bb = bh >> 2, h = bh & 3;
#pragma unroll
    for (int r = 0; r < 4; r++) {
        float inv = 1.f / li[r];
        size_t trow = (size_t)bb * SEQ + qt * 64 + w * 16 + quad * 4 + r;
#pragma unroll
        for (int nb = 0; nb < 4; nb++)
            o[trow * 256 + h * 64 + nb * 16 + l15] = f2bs(oacc[nb][r] * inv);
    }
}

// ------------------------------------------------------------------ gemm ----
// C[16384 x 256] = A @ WT^T + bias (fp32 bias), epilogues:
// MODE 0: + xt residual, store bf16 av -> outb16
// MODE 1: exact GELU, store bf16       -> outb16
// MODE 2: + avin residual, store fp32 transposed [b][c][sp] -> outf
template<int MODE>
__global__ __launch_bounds__(256) void gemm_kernel(
    const short* A, const short* WT, const float* bias,
    const short* xt, const short* avin, short* outb16, float* outf)
{
    int tid = threadIdx.x;
    int w = tid >> 6, lane = tid & 63, quad = lane >> 4, l15 = lane & 15;
    int m0 = blockIdx.x * 64 + w * 16;
    int arow = m0 + l15;

    float4_ acc[16];
#pragma unroll
    for (int nb = 0; nb < 16; nb++) {
        float bvv = bias[nb * 16 + l15];
        acc[nb] = {bvv, bvv, bvv, bvv};
    }

    for (int kc = 0; kc < 8; kc++) {
        short8 a = *(const short8*)(A + (size_t)arow * 256 + kc * 32 + quad * 8);
#pragma unroll
        for (int nb = 0; nb < 16; nb++) {
            short8 b = *(const short8*)(WT + (size_t)(nb * 16 + l15) * 256 + kc * 32 + quad * 8);
            acc[nb] = MFMA16(a, b, acc[nb]);
        }
    }

    int bb = m0 >> 12;
    int sp0 = (m0 & 4095) + quad * 4;
#pragma unroll
    for (int nb = 0; nb < 16; nb++) {
        int col = nb * 16 + l15;
        if (MODE == 0) {
#pragma unroll
            for (int r = 0; r < 4; r++) {
                size_t t = (size_t)m0 + quad * 4 + r;
                float v = acc[nb][r] + s2f(xt[t * 256 + col]);
                outb16[t * 256 + col] = f2bs(v);
            }
        } else if (MODE == 1) {
#pragma unroll
            for (int r = 0; r < 4; r++) {
                size_t t = (size_t)m0 + quad * 4 + r;
                float v = acc[nb][r];
                v = 0.5f * v * (1.f + erff(v * 0.70710678118f));
                outb16[t * 256 + col] = f2bs(v);
            }
        } else {
            float4_ pk;
#pragma unroll
            for (int r = 0; r < 4; r++) {
                size_t t = (size_t)m0 + quad * 4 + r;
                pk[r] = acc[nb][r] + s2f(avin[t * 256 + col]);
            }
            *(float4_*)(outf + ((size_t)bb * 256 + col) * SEQ + sp0) = pk;
        }
    }
}

// ------------------------------------------------------------------- ln2 ----
// av bf16 [t][c] -> xn2 bf16 [t][c]
__global__ __launch_bounds__(256) void ln2_kernel(
    const short* av, const float* g, const float* bta, short* xn2)
{
    int w = threadIdx.x >> 6, lane = threadIdx.x & 63;
    int t = blockIdx.x * 4 + w;
    const short* row = av + (size_t)t * 256;
    short4_ raw = *(const short4_*)(row + lane * 4);
    float v0 = s2f(raw[0]), v1 = s2f(raw[1]), v2 = s2f(raw[2]), v3 = s2f(raw[3]);
    float sum = v0 + v1 + v2 + v3;
    float ss = v0 * v0 + v1 * v1 + v2 * v2 + v3 * v3;
#pragma unroll
    for (int off = 1; off < 64; off <<= 1) {
        sum += __shfl_xor(sum, off);
        ss += __shfl_xor(ss, off);
    }
    float mu = sum * (1.f / 256.f);
    float var = ss * (1.f / 256.f) - mu * mu;
    float rs = rsqrtf(var + 1e-5f);
    float vv[4] = {v0, v1, v2, v3};
    short4_ pk;
#pragma unroll
    for (int j = 0; j < 4; j++) {
        int c = lane * 4 + j;
        pk[j] = f2bs((vv[j] - mu) * rs * g[c] + bta[c]);
    }
    *(short4_*)(xn2 + (size_t)t * 256 + lane * 4) = pk;
}

// ---------------------------------------------------------------- launch ----
// fp32 I/O per reference (jnp.float32 everywhere); bf16 internals for MFMA.
// d_out (16 MB fp32) doubles as scratch:
//   lower 8 MB: q bf16 (dead after flash)
//   upper 8 MB: xn bf16 (dead after qkv) -> o bf16 (dead after gemm<0>)
//   final gemm<2> writes all of d_out; inputs t1/av live in ws -> no race.
// ws peak = 0.5 MB weights + xt 8 + k 8 + vt 8 = 24.5 MB:
//   av bf16 over k (dead after flash); xn2 over xt; t1 over vt.
extern "C" void kernel_launch(void* const* d_in, const int* in_sizes, int n_in,
                              void* d_out, int out_size, void* d_ws, size_t ws_size,
                              hipStream_t stream)
{
    const float* x     = (const float*)d_in[0];
    const float* ln1_g = (const float*)d_in[1];
    const float* ln1_b = (const float*)d_in[2];
    const float* wq    = (const float*)d_in[3];
    const float* bq    = (const float*)d_in[4];
    const float* wk    = (const float*)d_in[5];
    const float* bk    = (const float*)d_in[6];
    const float* wv    = (const float*)d_in[7];
    const float* bv    = (const float*)d_in[8];
    const float* wo    = (const float*)d_in[9];
    const float* bo    = (const float*)d_in[10];
    const float* ln2_g = (const float*)d_in[11];
    const float* ln2_b = (const float*)d_in[12];
    const float* w1    = (const float*)d_in[13];
    const float* b1    = (const float*)d_in[14];
    const float* w2    = (const float*)d_in[15];
    const float* b2    = (const float*)d_in[16];

    char* ws = (char*)d_ws;
    const size_t SZ_BF = (size_t)TOK * 256 * 2;  // 8 MB

    short* wqT = (short*)(ws + 0);
    short* wkT = (short*)(ws + 8192);
    short* wvT = (short*)(ws + 16384);
    short* woT = (short*)(ws + 24576);
    short* w1T = (short*)(ws + 155648);
    short* w2T = (short*)(ws + 286720);
    char* base = ws + 524288;                 // 512 KB weight region (padded)

    short* xt  = (short*)(base);              // +0 MB   (ws)
    short* kbuf= (short*)(base + SZ_BF);      // +8 MB   (ws)
    short* vtb = (short*)(base + 2 * SZ_BF);  // +16 MB  (ws, end 24.5 MB)

    short* qb  = (short*)d_out;                         // d_out lower 8 MB
    short* xn  = (short*)((char*)d_out + SZ_BF);        // d_out upper 8 MB
    short* ob  = xn;                                    // o over xn (xn dead after qkv)
    short* av  = kbuf;                                  // av bf16 over k (dead after flash)
    short* xn2 = xt;                                    // over xt (dead after gemm<0>)
    short* t1  = vtb;                                   // over vt (dead after flash)

    repack_kernel<<<816, 256, 0, stream>>>(wq, wk, wv, wo, w1, w2,
                                           wqT, wkT, wvT, woT, w1T, w2T);
    ln1_kernel<<<TOK / 64, 64, 0, stream>>>(x, ln1_g, ln1_b, xn, xt);
    qkv_kernel<<<TOK / 64, 256, 0, stream>>>(xn, wqT, wkT, wvT, bq, bk, bv,
                                             qb, kbuf, vtb);
    flash_kernel<<<dim3(64, 16), 256, 0, stream>>>(qb, kbuf, vtb, ob);
    gemm_kernel<0><<<TOK / 64, 256, 0, stream>>>(ob, woT, bo, xt, nullptr, av, nullptr);
    ln2_kernel<<<TOK / 4, 256, 0, stream>>>(av, ln2_g, ln2_b, xn2);
    gemm_kernel<1><<<TOK / 64, 256, 0, stream>>>(xn2, w1T, b1, nullptr, nullptr, t1, nullptr);
    gemm_kernel<2><<<TOK / 64, 256, 0, stream>>>(t1, w2T, b2, nullptr, av, nullptr, (float*)d_out);
}

// Round 5
// 396.788 us; speedup vs baseline: 1.2104x; 1.2104x over previous
//
#include <hip/hip_runtime.h>
#include <hip/hip_bf16.h>
#include <cstdint>

typedef __attribute__((ext_vector_type(8))) short short8;
typedef __attribute__((ext_vector_type(4))) short short4_;
typedef __attribute__((ext_vector_type(4))) float float4_;

#define MFMA16(a,b,c)  __builtin_amdgcn_mfma_f32_16x16x32_bf16(a,b,c,0,0,0)
#define MFMA16K16(a,b,c) __builtin_amdgcn_mfma_f32_16x16x16bf16_1k(a,b,c,0,0,0)

__device__ __forceinline__ short f2bs(float f) {
    __hip_bfloat16 h = __float2bfloat16(f);
    return *reinterpret_cast<short*>(&h);
}
__device__ __forceinline__ float s2f(short s) {
    return __bfloat162float(*reinterpret_cast<__hip_bfloat16*>(&s));
}

static const int EMB = 256;
static const int SEQ = 4096;   // 64*64 spatial
static const int TOK = 16384;  // BS * SEQ

// ---------------------------------------------------------------- repack ----
// (round-3 verbatim)
__global__ __launch_bounds__(256) void repack_kernel(
    const float* wq, const float* wk, const float* wv,
    const float* wo, const float* w1, const float* w2,
    short* wqT, short* wkT, short* wvT, short* woT, short* w1T, short* w2T)
{
    int idx = blockIdx.x * 256 + threadIdx.x;
    if (idx < 3 * 4096) {
        int m = idx / 4096, r = idx % 4096;
        int n = r / 64, k = r % 64;
        const float* src = (m == 0) ? wq : (m == 1) ? wk : wv;
        short* dst = (m == 0) ? wqT : (m == 1) ? wkT : wvT;
        float v = src[k * 64 + n];
        if (m == 0) v *= 0.125f;
        dst[n * 64 + k] = f2bs(v);
    } else {
        int idx2 = idx - 3 * 4096;
        if (idx2 < 3 * 65536) {
            int m = idx2 / 65536, r = idx2 % 65536;
            int n = r / 256, k = r % 256;
            const float* src = (m == 0) ? wo : (m == 1) ? w1 : w2;
            short* dst = (m == 0) ? woT : (m == 1) ? w1T : w2T;
            dst[n * 256 + k] = f2bs(src[k * 256 + n]);
        }
    }
}

// ------------------------------------------------------------------- ln1 ----
// (round-3 verbatim: 64-thread blocks, one token per thread)
__global__ __launch_bounds__(64) void ln1_kernel(
    const float* x, const float* g, const float* bta,
    short* xn, short* xt)
{
    int t = blockIdx.x * 64 + threadIdx.x;
    int b = t >> 12, sp = t & 4095;
    const float* xb = x + (size_t)b * EMB * SEQ + sp;
    float sum = 0.f, ss = 0.f;
#pragma unroll 8
    for (int c = 0; c < 256; c++) {
        float v = xb[(size_t)c * SEQ];
        sum += v; ss += v * v;
    }
    float mu = sum * (1.f / 256.f);
    float var = ss * (1.f / 256.f) - mu * mu;
    float rs = rsqrtf(var + 1e-5f);
    short* xnr = xn + (size_t)t * 256;
    short* xtr = xt + (size_t)t * 256;
#pragma unroll 8
    for (int c = 0; c < 256; c++) {
        float v = xb[(size_t)c * SEQ];
        xtr[c] = f2bs(v);
        xnr[c] = f2bs((v - mu) * rs * g[c] + bta[c]);
    }
}

// ------------------------------------------------------------------- qkv ----
// (round-3 verbatim: grid TOK/64, all 4 heads per block)
__global__ __launch_bounds__(256) void qkv_kernel(
    const short* xn, const short* wqT, const short* wkT, const short* wvT,
    const float* bq, const float* bk, const float* bv,
    short* qo, short* ko, short* vto)
{
    int tid = threadIdx.x;
    int w = tid >> 6, lane = tid & 63, quad = lane >> 4, l15 = lane & 15;
    int m0 = blockIdx.x * 64 + w * 16;
    int row = m0 + l15;
    int bb = row >> 12;
    int s0 = (m0 & 4095) + quad * 4;

    for (int h = 0; h < 4; h++) {
        short8 a0 = *(const short8*)(xn + (size_t)row * 256 + h * 64 + quad * 8);
        short8 a1 = *(const short8*)(xn + (size_t)row * 256 + h * 64 + 32 + quad * 8);
        size_t headbase = (size_t)(bb * 4 + h) * SEQ;
#pragma unroll
        for (int p = 0; p < 3; p++) {
            const short* WT = (p == 0) ? wqT : (p == 1) ? wkT : wvT;
            const float* bias = (p == 0) ? bq : (p == 1) ? bk : bv;
            float bscale = (p == 0) ? 0.125f : 1.f;
#pragma unroll
            for (int nb = 0; nb < 4; nb++) {
                int col = nb * 16 + l15;
                short8 b0 = *(const short8*)(WT + col * 64 + quad * 8);
                short8 b1 = *(const short8*)(WT + col * 64 + 32 + quad * 8);
                float bvv = bias[col] * bscale;
                float4_ acc = {bvv, bvv, bvv, bvv};
                acc = MFMA16(a0, b0, acc);
                acc = MFMA16(a1, b1, acc);
                if (p < 2) {
                    short* dst = (p == 0) ? qo : ko;
#pragma unroll
                    for (int r = 0; r < 4; r++)
                        dst[(headbase + s0 + r) * 64 + col] = f2bs(acc[r]);
                } else {
                    short4_ pk;
#pragma unroll
                    for (int r = 0; r < 4; r++) pk[r] = f2bs(acc[r]);
                    *(short4_*)(vto + ((size_t)(bb * 4 + h) * 64 + col) * SEQ + s0) = pk;
                }
            }
        }
    }
}

// ----------------------------------------------------------------- flash ----
// BISECT: the ONLY kernel changed vs the round-3 passing build.
// S^T formulation: S^T = K·Q^T (swapped MFMA operands) -> each LANE owns one
// query column; softmax state scalar/thread (2 shuffles vs 32); P^T C-layout
// == 16x16x16 B-operand layout -> PV needs only a register pack, no LDS trip.
__global__ __launch_bounds__(256) void flash_kernel(
    const short* q, const short* k, const short* vt, short* o)
{
    __shared__ short K_lds[64 * 72];
    __shared__ short V_lds[64 * 72];

    int tid = threadIdx.x;
    int w = tid >> 6, lane = tid & 63, quad = lane >> 4, l15 = lane & 15;
    int qt = blockIdx.x, bh = blockIdx.y;

    const short* qb = q + (size_t)bh * SEQ * 64;
    const short* kb = k + (size_t)bh * SEQ * 64;
    const short* vb = vt + (size_t)bh * 64 * SEQ;

    // Q fragment: B-operand layout B[k=quad*8+j][n=l15] == Q[l15][quad*8+j]
    int qrow = qt * 64 + w * 16 + l15;
    short8 qf0 = *(const short8*)(qb + (size_t)qrow * 64 + quad * 8);
    short8 qf1 = *(const short8*)(qb + (size_t)qrow * 64 + 32 + quad * 8);

    float4_ oacc[4];   // O^T[d = md*16 + quad*4 + r][query = l15]
#pragma unroll
    for (int md = 0; md < 4; md++) oacc[md] = {0.f, 0.f, 0.f, 0.f};
    float mi = -1e30f, li = 0.f;

    int srow = tid >> 2;          // 0..63
    int sc0 = (tid & 3) * 8;      // shorts

    for (int kt = 0; kt < 64; kt++) {
        __syncthreads();
#pragma unroll
        for (int i = 0; i < 2; i++) {
            *(short8*)&K_lds[srow * 72 + sc0 + i * 32] =
                *(const short8*)(kb + (size_t)(kt * 64 + srow) * 64 + sc0 + i * 32);
            *(short8*)&V_lds[srow * 72 + sc0 + i * 32] =
                *(const short8*)(vb + (size_t)srow * SEQ + kt * 64 + sc0 + i * 32);
        }
        __syncthreads();

        // S^T = K·Q^T: s[nb][r] = S^T[key = nb*16 + quad*4 + r][query = l15]
        float4_ s[4];
#pragma unroll
        for (int nb = 0; nb < 4; nb++) {
            float4_ a = {0.f, 0.f, 0.f, 0.f};
            short8 k0 = *(const short8*)&K_lds[(nb * 16 + l15) * 72 + quad * 8];
            short8 k1 = *(const short8*)&K_lds[(nb * 16 + l15) * 72 + 32 + quad * 8];
            a = MFMA16(k0, qf0, a);
            a = MFMA16(k1, qf1, a);
            s[nb] = a;
        }

        // online softmax: one query per lane; reduce across quads (xor16/32)
        float mloc = s[0][0];
#pragma unroll
        for (int nb = 0; nb < 4; nb++)
#pragma unroll
            for (int r = 0; r < 4; r++) mloc = fmaxf(mloc, s[nb][r]);
        mloc = fmaxf(mloc, __shfl_xor(mloc, 16));
        mloc = fmaxf(mloc, __shfl_xor(mloc, 32));
        float mnew = fmaxf(mi, mloc);
        float alpha = __expf(mi - mnew);
        mi = mnew;

        float rsum = 0.f;
#pragma unroll
        for (int nb = 0; nb < 4; nb++)
#pragma unroll
            for (int r = 0; r < 4; r++) {
                s[nb][r] = __expf(s[nb][r] - mnew);
                rsum += s[nb][r];
            }
        rsum += __shfl_xor(rsum, 16);
        rsum += __shfl_xor(rsum, 32);
        li = li * alpha + rsum;
#pragma unroll
        for (int md = 0; md < 4; md++) {
            oacc[md][0] *= alpha; oacc[md][1] *= alpha;
            oacc[md][2] *= alpha; oacc[md][3] *= alpha;
        }

        // pack P^T: C-layout (k=quad*4+r) IS the 16x16x16 B-operand layout
        short4_ pf[4];
#pragma unroll
        for (int nb = 0; nb < 4; nb++)
#pragma unroll
            for (int r = 0; r < 4; r++) pf[nb][r] = f2bs(s[nb][r]);

        // O^T += V^T · P^T  (A = V^T-frag A[m=d][k=key], K=16 per nb)
#pragma unroll
        for (int md = 0; md < 4; md++)
#pragma unroll
            for (int nb = 0; nb < 4; nb++) {
                short4_ vf = *(const short4_*)&V_lds[(md * 16 + l15) * 72 + nb * 16 + quad * 4];
                oacc[md] = MFMA16K16(vf, pf[nb], oacc[md]);
            }
    }

    // epilogue: o[token][h*64 + d], token = bb*SEQ + qt*64 + w*16 + l15
    int bb = bh >> 2, h = bh & 3;
    float inv = 1.f / li;
    size_t trow = (size_t)bb * SEQ + qt * 64 + w * 16 + l15;
#pragma unroll
    for (int md = 0; md < 4; md++) {
        short4_ pk;
#pragma unroll
        for (int r = 0; r < 4; r++) pk[r] = f2bs(oacc[md][r] * inv);
        *(short4_*)(o + trow * 256 + h * 64 + md * 16 + quad * 4) = pk;
    }
}

// ------------------------------------------------------------------ gemm ----
// (round-3 verbatim: 16 acc blocks, grid TOK/64)
template<int MODE>
__global__ __launch_bounds__(256) void gemm_kernel(
    const short* A, const short* WT, const float* bias,
    const short* xt, const short* avin, short* outb16, float* outf)
{
    int tid = threadIdx.x;
    int w = tid >> 6, lane = tid & 63, quad = lane >> 4, l15 = lane & 15;
    int m0 = blockIdx.x * 64 + w * 16;
    int arow = m0 + l15;

    float4_ acc[16];
#pragma unroll
    for (int nb = 0; nb < 16; nb++) {
        float bvv = bias[nb * 16 + l15];
        acc[nb] = {bvv, bvv, bvv, bvv};
    }

    for (int kc = 0; kc < 8; kc++) {
        short8 a = *(const short8*)(A + (size_t)arow * 256 + kc * 32 + quad * 8);
#pragma unroll
        for (int nb = 0; nb < 16; nb++) {
            short8 b = *(const short8*)(WT + (size_t)(nb * 16 + l15) * 256 + kc * 32 + quad * 8);
            acc[nb] = MFMA16(a, b, acc[nb]);
        }
    }

    int bb = m0 >> 12;
    int sp0 = (m0 & 4095) + quad * 4;
#pragma unroll
    for (int nb = 0; nb < 16; nb++) {
        int col = nb * 16 + l15;
        if (MODE == 0) {
#pragma unroll
            for (int r = 0; r < 4; r++) {
                size_t t = (size_t)m0 + quad * 4 + r;
                float v = acc[nb][r] + s2f(xt[t * 256 + col]);
                outb16[t * 256 + col] = f2bs(v);
            }
        } else if (MODE == 1) {
#pragma unroll
            for (int r = 0; r < 4; r++) {
                size_t t = (size_t)m0 + quad * 4 + r;
                float v = acc[nb][r];
                v = 0.5f * v * (1.f + erff(v * 0.70710678118f));
                outb16[t * 256 + col] = f2bs(v);
            }
        } else {
            float4_ pk;
#pragma unroll
            for (int r = 0; r < 4; r++) {
                size_t t = (size_t)m0 + quad * 4 + r;
                pk[r] = acc[nb][r] + s2f(avin[t * 256 + col]);
            }
            *(float4_*)(outf + ((size_t)bb * 256 + col) * SEQ + sp0) = pk;
        }
    }
}

// ------------------------------------------------------------------- ln2 ----
// (round-3 verbatim)
__global__ __launch_bounds__(256) void ln2_kernel(
    const short* av, const float* g, const float* bta, short* xn2)
{
    int w = threadIdx.x >> 6, lane = threadIdx.x & 63;
    int t = blockIdx.x * 4 + w;
    const short* row = av + (size_t)t * 256;
    short4_ raw = *(const short4_*)(row + lane * 4);
    float v0 = s2f(raw[0]), v1 = s2f(raw[1]), v2 = s2f(raw[2]), v3 = s2f(raw[3]);
    float sum = v0 + v1 + v2 + v3;
    float ss = v0 * v0 + v1 * v1 + v2 * v2 + v3 * v3;
#pragma unroll
    for (int off = 1; off < 64; off <<= 1) {
        sum += __shfl_xor(sum, off);
        ss += __shfl_xor(ss, off);
    }
    float mu = sum * (1.f / 256.f);
    float var = ss * (1.f / 256.f) - mu * mu;
    float rs = rsqrtf(var + 1e-5f);
    float vv[4] = {v0, v1, v2, v3};
    short4_ pk;
#pragma unroll
    for (int j = 0; j < 4; j++) {
        int c = lane * 4 + j;
        pk[j] = f2bs((vv[j] - mu) * rs * g[c] + bta[c]);
    }
    *(short4_*)(xn2 + (size_t)t * 256 + lane * 4) = pk;
}

// ---------------------------------------------------------------- launch ----
// (round-3 verbatim launch config + aliasing — proven to pass post-timing)
extern "C" void kernel_launch(void* const* d_in, const int* in_sizes, int n_in,
                              void* d_out, int out_size, void* d_ws, size_t ws_size,
                              hipStream_t stream)
{
    const float* x     = (const float*)d_in[0];
    const float* ln1_g = (const float*)d_in[1];
    const float* ln1_b = (const float*)d_in[2];
    const float* wq    = (const float*)d_in[3];
    const float* bq    = (const float*)d_in[4];
    const float* wk    = (const float*)d_in[5];
    const float* bk    = (const float*)d_in[6];
    const float* wv    = (const float*)d_in[7];
    const float* bv    = (const float*)d_in[8];
    const float* wo    = (const float*)d_in[9];
    const float* bo    = (const float*)d_in[10];
    const float* ln2_g = (const float*)d_in[11];
    const float* ln2_b = (const float*)d_in[12];
    const float* w1    = (const float*)d_in[13];
    const float* b1    = (const float*)d_in[14];
    const float* w2    = (const float*)d_in[15];
    const float* b2    = (const float*)d_in[16];

    char* ws = (char*)d_ws;
    const size_t SZ_BF = (size_t)TOK * 256 * 2;  // 8 MB

    short* wqT = (short*)(ws + 0);
    short* wkT = (short*)(ws + 8192);
    short* wvT = (short*)(ws + 16384);
    short* woT = (short*)(ws + 24576);
    short* w1T = (short*)(ws + 155648);
    short* w2T = (short*)(ws + 286720);
    char* base = ws + 524288;

    short* xt  = (short*)(base);
    short* kbuf= (short*)(base + SZ_BF);
    short* vtb = (short*)(base + 2 * SZ_BF);

    short* qb  = (short*)d_out;
    short* xn  = (short*)((char*)d_out + SZ_BF);
    short* ob  = xn;
    short* av  = kbuf;
    short* xn2 = xt;
    short* t1  = vtb;

    repack_kernel<<<816, 256, 0, stream>>>(wq, wk, wv, wo, w1, w2,
                                           wqT, wkT, wvT, woT, w1T, w2T);
    ln1_kernel<<<TOK / 64, 64, 0, stream>>>(x, ln1_g, ln1_b, xn, xt);
    qkv_kernel<<<TOK / 64, 256, 0, stream>>>(xn, wqT, wkT, wvT, bq, bk, bv,
                                             qb, kbuf, vtb);
    flash_kernel<<<dim3(64, 16), 256, 0, stream>>>(qb, kbuf, vtb, ob);
    gemm_kernel<0><<<TOK / 64, 256, 0, stream>>>(ob, woT, bo, xt, nullptr, av, nullptr);
    ln2_kernel<<<TOK / 4, 256, 0, stream>>>(av, ln2_g, ln2_b, xn2);
    gemm_kernel<1><<<TOK / 64, 256, 0, stream>>>(xn2, w1T, b1, nullptr, nullptr, t1, nullptr);
    gemm_kernel<2><<<TOK / 64, 256, 0, stream>>>(t1, w2T, b2, nullptr, av, nullptr, (float*)d_out);
}